// Round 20
// baseline (223.421 us; speedup 1.0000x reference)
//
#include <hip/hip_runtime.h>
#include <hip/hip_fp16.h>
#include <math.h>

typedef _Float16 f16x8 __attribute__((ext_vector_type(8)));
typedef _Float16 f16x4 __attribute__((ext_vector_type(4)));
typedef float    f32x4 __attribute__((ext_vector_type(4)));

#define M_TOT 32768   // 8*64*64 pixels
#define VROW  4608    // padded vT row: 64 y * 72 x
#define LOG2E 1.44269504088896f

// ---------------------------------------------------------------------------
// async global->LDS, 16B per lane. LDS dest = wave-uniform base + lane*16.
// ---------------------------------------------------------------------------
__device__ __forceinline__ void gload16(const void* g, void* l) {
    __builtin_amdgcn_global_load_lds(
        (const __attribute__((address_space(1))) unsigned int*)g,
        (__attribute__((address_space(3))) unsigned int*)l, 16, 0, 0);
}

__device__ __forceinline__ f32x4 mfma32(f16x8 a, f16x8 b, f32x4 c) {
    return __builtin_amdgcn_mfma_f32_16x16x32_f16(a, b, c, 0, 0, 0);
}

// ---------------------------------------------------------------------------
// merged prep: weights->fp16^T (log2e folded into wq) | vTp borders
//              | posT MFMA-A layout | zero page.  (no x conversion — proj
//              stages A directly from fp32 x via async global_load_lds.)
// ---------------------------------------------------------------------------
__global__ __launch_bounds__(256) void prep(
    const float* __restrict__ wq, const float* __restrict__ wkv,
    const float* __restrict__ wout,
    const float* __restrict__ posw, const float* __restrict__ posh,
    __half* __restrict__ wT, __half* __restrict__ woT,
    __half* __restrict__ posT, __half* __restrict__ vTp, __half* __restrict__ zp)
{
    const int bid = blockIdx.x, t = threadIdx.x;
    if (bid < 4096) {                       // weights transposed
        const int id = bid * 256 + t;
        const int nr = id >> 9, k = id & 511;
        if (nr < 512) {
            wT[(size_t)nr * 512 + k] = __float2half(wq[k * 512 + nr] * (0.125f * LOG2E));
        } else if (nr < 1536) {
            wT[(size_t)nr * 512 + k] = __float2half(wkv[k * 1024 + (nr - 512)]);
        } else {
            woT[(size_t)(nr - 1536) * 512 + k] = __float2half(wout[k * 512 + (nr - 1536)]);
        }
    } else if (bid < 6144) {               // vTp x-borders -> 0
        const int id = (bid - 4096) * 256 + t;
        const int row = id >> 7, rem = id & 127;
        const int y = rem >> 1, side = rem & 1;
        f16x4 z = {(_Float16)0.f, (_Float16)0.f, (_Float16)0.f, (_Float16)0.f};
        *(f16x4*)(vTp + (size_t)row * VROW + y * 72 + side * 68) = z;
    } else if (bid < 6160) {               // posT [tb][idx(32)][d(64)]
        const int id = (bid - 6144) * 256 + t;
        const int tb = id >> 11, idx = (id >> 6) & 31, d = id & 63;
        const float* src = tb ? posh : posw;
        posT[id] = __float2half((idx < 31) ? src[d * 31 + idx] : 0.f);
    } else {                                // zero page (256 B)
        if (t < 16) {
            float4 z = make_float4(0.f, 0.f, 0.f, 0.f);
            *(float4*)(zp + t * 8) = z;
        }
    }
}

// ---------------------------------------------------------------------------
// fp16 MFMA GEMM, BM=BN=128, BK=64, 4 waves, single-buffered (r15-proven
// loop).  1-D grid, XCD-partitioned (no half split — r15 best mapping).
// MODE 0: A = fp32 x staged ASYNC via global_load_lds (32 KB tile, source
//         chunk-permuted c^(row&15) -> fragment reads ~2-way bank-free);
//         fp32->fp16 convert (RN) at fragment-assembly. Epilogue -> q16,
//         k16, vTp. NBN=12.
// MODE 1: A = fp16 o16 via global_load_lds (XOR(row&7) swizzle); fp32 out.
//         NBN=4.
// ---------------------------------------------------------------------------
template <int MODE, int NBN>
__global__ __launch_bounds__(256) void mfma_gemm(
    const void* __restrict__ A, const __half* __restrict__ Bt,
    __half* __restrict__ q16, __half* __restrict__ k16, __half* __restrict__ vTp,
    float* __restrict__ outf)
{
    __shared__ __align__(16) char As[(MODE == 0) ? 32768 : 16384];
    __shared__ __align__(16) char Bs[16384];

    const int t = threadIdx.x;
    const int l = t & 63, w = t >> 6;
    const int wr = w >> 1, wc = w & 1;
    const int lr = l & 15, hi = l >> 4;

    // XCD partition (RR dispatch: xcd = bid & 7)
    const int bid = blockIdx.x;
    const int xcd = bid & 7, loc = bid >> 3;       // loc < 32*NBN
    const int bm  = xcd * 32 + (loc & 31);
    const int bn  = loc >> 5;

    const float*  Af = (const float*)A;
    const __half* Ah = (const __half*)A;

    f32x4 acc[4][4];
    #pragma unroll
    for (int i = 0; i < 4; ++i)
        #pragma unroll
        for (int j = 0; j < 4; ++j) acc[i][j] = (f32x4){0.f, 0.f, 0.f, 0.f};

    const int sch = (t & 7);

    for (int k0 = 0; k0 < 512; k0 += 64) {
        if (MODE == 0) {
            // A fp32: 2048 16B-chunks; [row][16 chunk] linear dest, source
            // chunk permuted by c ^ (row & 15)
            #pragma unroll
            for (int it = 0; it < 8; ++it) {
                const int cid = it * 256 + t;
                const int row = cid >> 4, c = cid & 15;
                gload16(Af + (size_t)(bm * 128 + row) * 512 + k0 + ((c ^ (row & 15)) << 2),
                        As + (it * 256 + w * 64) * 16);
            }
        } else {
            #pragma unroll
            for (int it = 0; it < 4; ++it) {
                const int row = it * 32 + (t >> 3);
                const int kk  = k0 + ((sch ^ (row & 7)) * 8);
                gload16(Ah + (size_t)(bm * 128 + row) * 512 + kk,
                        As + (it * 256 + w * 64) * 16);
            }
        }
        #pragma unroll
        for (int it = 0; it < 4; ++it) {
            const int row = it * 32 + (t >> 3);
            const int kk  = k0 + ((sch ^ (row & 7)) * 8);
            gload16(Bt + (size_t)(bn * 128 + row) * 512 + kk,
                    Bs + (it * 256 + w * 64) * 16);
        }
        __syncthreads();

        #pragma unroll
        for (int dc = 0; dc < 2; ++dc) {
            f16x8 af[4], bf[4];
            #pragma unroll
            for (int i = 0; i < 4; ++i) {
                const int ra = wr * 64 + i * 16 + lr;
                if (MODE == 0) {
                    const int s  = ra & 15;
                    const int c0 = dc * 8 + hi * 2;      // even data-chunk index
                    const int pA = ra * 256 + ((c0 ^ s) << 4);
                    const int pB = ra * 256 + (((c0 ^ s) ^ 1) << 4);
                    const float4 fA = *(const float4*)(As + pA);
                    const float4 fB = *(const float4*)(As + pB);
                    __half2 hh[4];
                    hh[0] = __floats2half2_rn(fA.x, fA.y);
                    hh[1] = __floats2half2_rn(fA.z, fA.w);
                    hh[2] = __floats2half2_rn(fB.x, fB.y);
                    hh[3] = __floats2half2_rn(fB.z, fB.w);
                    af[i] = *(f16x8*)hh;
                } else {
                    af[i] = *(const f16x8*)(As + ra * 128 + (((dc * 4 + hi) ^ (ra & 7)) * 16));
                }
            }
            #pragma unroll
            for (int j = 0; j < 4; ++j) {
                const int rb = wc * 64 + j * 16 + lr;
                bf[j] = *(const f16x8*)(Bs + rb * 128 + (((dc * 4 + hi) ^ (rb & 7)) * 16));
            }
            #pragma unroll
            for (int i = 0; i < 4; ++i)
                #pragma unroll
                for (int j = 0; j < 4; ++j)
                    acc[i][j] = mfma32(af[i], bf[j], acc[i][j]);
        }
        __syncthreads();
    }

    const int lq = hi;
    #pragma unroll
    for (int i = 0; i < 4; ++i) {
        #pragma unroll
        for (int j = 0; j < 4; ++j) {
            const int row0 = bm * 128 + wr * 64 + i * 16 + lq * 4;
            const int col  = bn * 128 + wc * 64 + j * 16 + lr;
            if (MODE == 1) {
                #pragma unroll
                for (int r = 0; r < 4; ++r)
                    outf[(size_t)(row0 + r) * 512 + col] = acc[i][j][r];
            } else if (bn < 4) {
                #pragma unroll
                for (int r = 0; r < 4; ++r)
                    q16[(size_t)(row0 + r) * 512 + col] = __float2half(acc[i][j][r]);
            } else if (wc == 0) {           // key part
                const int head = bn - 4, d2 = j * 16 + lr;
                #pragma unroll
                for (int r = 0; r < 4; ++r)
                    k16[(size_t)(row0 + r) * 512 + head * 64 + d2] = __float2half(acc[i][j][r]);
            } else {                        // value part -> vTp[(b*8+head)*64+d][y*72+x+4]
                const int head = bn - 4, d2 = j * 16 + lr;
                const int bb = row0 >> 12, pix = row0 & 4095;  // 4 consecutive x, same y
                const int py = pix >> 6, px = pix & 63;
                f16x4 pv;
                #pragma unroll
                for (int r = 0; r < 4; ++r) pv[r] = (_Float16)acc[i][j][r];
                *(f16x4*)(vTp + ((size_t)((bb * 8 + head) * 64 + d2)) * VROW + py * 72 + px + 4) = pv;
            }
        }
    }
}

// ---------------------------------------------------------------------------
// MFMA halo attention, 4 waves, 3 barriers, LDS 40640 B -> 4 blocks/CU.
// Wave g owns key quarter [g*64,+64) for QK^T/softmax, dim quarter for PV.
// Pos bias: fp16 [23][66] tables; red2 overlays pos region after B1.
// Scores in log2 domain (log2e folded into wq) -> native exp2f.
// ---------------------------------------------------------------------------
__global__ __launch_bounds__(256, 4) void halo_attn(
    const __half* __restrict__ qbuf, const __half* __restrict__ kbuf,
    const __half* __restrict__ vTp, const __half* __restrict__ posT,
    const __half* __restrict__ zp, __half* __restrict__ obuf)
{
    __shared__ __align__(16) char KP[64 * 520];   // 33280 B: K(swz) -> P (pitch 520)
    __shared__ __align__(16) char POSB[6336];     // fp16 pos [2][24][66]; later red2
    __shared__ float red[4][64];                  // 1024 B

    __half* RW = (__half*)POSB;                   // [24][66] fp16, idx8 = idx-8
    __half* RH = (__half*)(POSB + 3168);
    float (*red2)[64] = (float(*)[64])POSB;       // overlay, live after B1

    // XCD swizzle: contiguous 512-block chunk (one batch) per XCD
    const int hw = blockIdx.x;
    const int wg = (hw & 7) * 512 + (hw >> 3);
    const int wb = wg & 7, hb = (wg >> 3) & 7, n = (wg >> 6) & 7, b = wg >> 9;
    const int t = threadIdx.x;
    const int l = t & 63, g = t >> 6;
    const int hi = l >> 4, c15 = l & 15;

    // ---- 1) issue K staging FIRST (global_load_lds, source pre-swizzled) ----
    #pragma unroll
    for (int it = 0; it < 8; ++it) {
        const int cid = it * 256 + t;
        const int S = cid * 16;                       // linear LDS byte
        const int row = S >> 7;                       // key 0..255
        const int d0h = (((S & 127) >> 4) ^ (row & 7)) * 8;   // halves
        const int ky = hb * 8 - 4 + (row >> 4);
        const int kx = wb * 8 - 4 + (row & 15);
        const bool ok = ((unsigned)ky < 64u) && ((unsigned)kx < 64u);
        const __half* src = ok ? (kbuf + ((size_t)((b * 64 + ky) * 64 + kx)) * 512 + n * 64 + d0h)
                               : zp;
        gload16(src, KP + (it * 256 + g * 64) * 16);
    }

    // ---- 2) V B-frags (16x16x32): lane (c15,hi) -> dim g*16+c15,
    //         keys kc*32 + hi*8 + j -> contiguous 16B in padded vT ----
    f16x8 vfrag[8];
    {
        const __half* vrow = vTp + ((size_t)((b * 8 + n) * 64 + g * 16 + c15)) * VROW;
        const int xoff = wb * 8 + (hi & 1) * 8;       // (wb*8-4 + kj0) + 4
        #pragma unroll
        for (int kc = 0; kc < 8; ++kc) {
            const int ki = kc * 2 + (hi >> 1);
            const int y = hb * 8 - 4 + ki;
            const __half* p = ((unsigned)y < 64u) ? (vrow + y * 72 + xoff) : zp;
            vfrag[kc] = *(const f16x8*)p;
        }
    }

    // ---- 3) Q fragments (B-operand of 16x16x32): qreg[qf][dc] ----
    f16x8 qreg[4][2];
    #pragma unroll
    for (int qf = 0; qf < 4; ++qf) {
        const int q = qf * 16 + c15;
        const size_t pix = (size_t)((b * 64 + hb * 8 + (q >> 3)) * 64 + wb * 8 + (q & 7));
        #pragma unroll
        for (int dc = 0; dc < 2; ++dc)
            qreg[qf][dc] = *(const f16x8*)(qbuf + pix * 512 + n * 64 + dc * 32 + hi * 8);
    }

    // ---- 4) pos MFMA straight from global posT (runs under K latency):
    //         wave g -> table tb=g>>1, idx-half ih=g&1 (8 MFMA) ----
    {
        const int tb = g >> 1, ih = g & 1;
        f32x4 accp[4];
        #pragma unroll
        for (int qf = 0; qf < 4; ++qf) accp[qf] = (f32x4){0.f, 0.f, 0.f, 0.f};
        #pragma unroll
        for (int dc = 0; dc < 2; ++dc) {
            const f16x8 a = *(const f16x8*)(posT + tb * 2048 + (ih * 16 + c15) * 64 + dc * 32 + hi * 8);
            #pragma unroll
            for (int qf = 0; qf < 4; ++qf)
                accp[qf] = mfma32(a, qreg[qf][dc], accp[qf]);
        }
        __half* dst = tb ? RH : RW;
        #pragma unroll
        for (int qf = 0; qf < 4; ++qf)
            #pragma unroll
            for (int r = 0; r < 4; ++r) {
                const unsigned idx8 = (unsigned)(ih * 16 + hi * 4 + r) - 8u;
                if (idx8 < 23u)
                    dst[idx8 * 66 + qf * 16 + c15] = __float2half(accp[qf][r]);
            }
    }
    __syncthreads();   // B0: K in LDS + pos tables visible (one combined barrier)

    // ---- QK^T: S^T frags, A=K (swizzled LDS, quarter g), B=Q regs ----
    f32x4 accs[4][4];
    #pragma unroll
    for (int kf = 0; kf < 4; ++kf)
        #pragma unroll
        for (int qf = 0; qf < 4; ++qf) accs[kf][qf] = (f32x4){0.f, 0.f, 0.f, 0.f};

    __builtin_amdgcn_s_setprio(1);
    #pragma unroll
    for (int kf = 0; kf < 4; ++kf) {
        const int row = g * 64 + kf * 16 + c15;
        #pragma unroll
        for (int dc = 0; dc < 2; ++dc) {
            const int off = (row * 128 + dc * 64 + hi * 16) ^ ((row & 7) << 4);
            f16x8 a = *(const f16x8*)(KP + off);
            #pragma unroll
            for (int qf = 0; qf < 4; ++qf)
                accs[kf][qf] = mfma32(a, qreg[qf][dc], accs[kf][qf]);
        }
    }
    __builtin_amdgcn_s_setprio(0);

    // ---- bias (fp16 tables) + per-quarter max ----
    float mq[4];
    #pragma unroll
    for (int qf = 0; qf < 4; ++qf) {
        const int q = qf * 16 + c15;
        const int qj = q & 7, qi = q >> 3;
        float pa[4], pb[4];
        #pragma unroll
        for (int r = 0; r < 4; ++r)  pa[r] = __half2float(RW[(hi * 4 + r + 7 - qj) * 66 + q]);
        #pragma unroll
        for (int kf = 0; kf < 4; ++kf) pb[kf] = __half2float(RH[(g * 4 + kf + 7 - qi) * 66 + q]);
        float mm = -1e30f;
        #pragma unroll
        for (int kf = 0; kf < 4; ++kf)
            #pragma unroll
            for (int r = 0; r < 4; ++r) {
                const float s = accs[kf][qf][r] + pa[r] + pb[kf];
                accs[kf][qf][r] = s;
                mm = fmaxf(mm, s);
            }
        mm = fmaxf(mm, __shfl_xor(mm, 16));
        mm = fmaxf(mm, __shfl_xor(mm, 32));
        mq[qf] = mm;
    }
    if (l < 16) {
        #pragma unroll
        for (int qf = 0; qf < 4; ++qf) red[g][qf * 16 + l] = mq[qf];
    }
    __syncthreads();   // B1: maxes visible; pos reads done -> POSB becomes red2

    // ---- exp2 + sums + pack P into LDS, pitch 520, 8B stores ----
    float sums[4];
    #pragma unroll
    for (int qf = 0; qf < 4; ++qf) {
        const int q = qf * 16 + c15;
        const float mfull = fmaxf(fmaxf(red[0][q], red[1][q]), fmaxf(red[2][q], red[3][q]));
        float ss = 0.f;
        #pragma unroll
        for (int kf = 0; kf < 4; ++kf)
            #pragma unroll
            for (int r = 0; r < 4; ++r) {
                const float p = exp2f(accs[kf][qf][r] - mfull);   // scores in log2 domain
                accs[kf][qf][r] = p;
                ss += p;
            }
        ss += __shfl_xor(ss, 16);
        ss += __shfl_xor(ss, 32);
        sums[qf] = ss;
        #pragma unroll
        for (int kf = 0; kf < 4; ++kf) {
            __half2 h01 = __floats2half2_rn(accs[kf][qf][0], accs[kf][qf][1]);
            __half2 h23 = __floats2half2_rn(accs[kf][qf][2], accs[kf][qf][3]);
            uint2 wv;
            wv.x = *(unsigned*)&h01;
            wv.y = *(unsigned*)&h23;
            *(uint2*)(KP + q * 520 + (g * 64 + kf * 16 + hi * 4) * 2) = wv;
        }
    }
    if (l < 16) {
        #pragma unroll
        for (int qf = 0; qf < 4; ++qf) red2[g][qf * 16 + l] = sums[qf];
    }
    __syncthreads();   // B2: P + sums visible

    // ---- PV via 16x16x32: wave g owns dims [g*16,+16), 8 kc steps. ----
    f32x4 acco[4];
    #pragma unroll
    for (int qf = 0; qf < 4; ++qf) acco[qf] = (f32x4){0.f, 0.f, 0.f, 0.f};
    __builtin_amdgcn_s_setprio(1);
    #pragma unroll
    for (int kc = 0; kc < 8; ++kc) {
        const f16x8 bf = vfrag[kc];
        #pragma unroll
        for (int qf = 0; qf < 4; ++qf) {
            const char* pp = KP + (qf * 16 + c15) * 520 + kc * 64 + hi * 16;
            const f16x4 p0 = *(const f16x4*)pp;
            const f16x4 p1 = *(const f16x4*)(pp + 8);
            const f16x8 af = __builtin_shufflevector(p0, p1, 0, 1, 2, 3, 4, 5, 6, 7);
            acco[qf] = mfma32(af, bf, acco[qf]);
        }
    }
    __builtin_amdgcn_s_setprio(0);

    // ---- normalize (fast rcp) + store ----
    #pragma unroll
    for (int qf = 0; qf < 4; ++qf) {
        #pragma unroll
        for (int r = 0; r < 4; ++r) {
            const int q = qf * 16 + hi * 4 + r;
            const float den = red2[0][q] + red2[1][q] + red2[2][q] + red2[3][q];
            const float v = acco[qf][r] * __builtin_amdgcn_rcpf(den);
            const size_t pix = (size_t)((b * 64 + hb * 8 + (q >> 3)) * 64 + wb * 8 + (q & 7));
            obuf[pix * 512 + n * 64 + g * 16 + c15] = __float2half(v);
        }
    }
}

// ---------------------------------------------------------------------------
extern "C" void kernel_launch(void* const* d_in, const int* in_sizes, int n_in,
                              void* d_out, int out_size, void* d_ws, size_t ws_size,
                              hipStream_t stream)
{
    const float* x    = (const float*)d_in[0];
    const float* wq   = (const float*)d_in[1];
    const float* wkv  = (const float*)d_in[2];
    const float* wout = (const float*)d_in[3];
    const float* posw = (const float*)d_in[4];
    const float* posh = (const float*)d_in[5];
    float* out = (float*)d_out;

    // fp16 workspace (~140 MB): proj reads fp32 x directly (async staged)
    const size_t NPIX = (size_t)M_TOT * 512;
    const size_t NVTP = (size_t)64 * 64 * VROW;    // 18.87M halves
    __half* wT   = (__half*)d_ws;            // 1.5 MB
    __half* woT  = wT + (size_t)1536 * 512;  // 0.5 MB
    __half* q16  = woT + (size_t)512 * 512;  // 33.5 MB
    __half* k16  = q16 + NPIX;               // 33.5 MB
    __half* vTp  = k16 + NPIX;               // 37.7 MB
    __half* o16  = vTp + NVTP;               // 33.5 MB
    __half* zp   = o16 + NPIX;               // 256 B zero page
    __half* posT = zp + 128;                 // 8 KB pos tables (MFMA-A layout)

    prep<<<6161, 256, 0, stream>>>(wq, wkv, wout, posw, posh,
                                   wT, woT, posT, vTp, zp);

    mfma_gemm<0, 12><<<3072, 256, 0, stream>>>(x, wT, q16, k16, vTp, nullptr);

    halo_attn<<<4096, 256, 0, stream>>>(q16, k16, vTp, posT, zp, o16);

    mfma_gemm<1, 4><<<1024, 256, 0, stream>>>(o16, woT, nullptr, nullptr, nullptr, out);
}

// Round 21
// 202.285 us; speedup vs baseline: 1.1045x; 1.1045x over previous
//
#include <hip/hip_runtime.h>
#include <hip/hip_fp16.h>
#include <math.h>

typedef _Float16 f16x8 __attribute__((ext_vector_type(8)));
typedef _Float16 f16x4 __attribute__((ext_vector_type(4)));
typedef float    f32x4 __attribute__((ext_vector_type(4)));

#define M_TOT 32768   // 8*64*64 pixels
#define VROW  4608    // padded vT row: 64 y * 72 x
#define LOG2E 1.44269504088896f

// ---------------------------------------------------------------------------
// async global->LDS, 16B per lane. LDS dest = wave-uniform base + lane*16.
// ---------------------------------------------------------------------------
__device__ __forceinline__ void gload16(const void* g, void* l) {
    __builtin_amdgcn_global_load_lds(
        (const __attribute__((address_space(1))) unsigned int*)g,
        (__attribute__((address_space(3))) unsigned int*)l, 16, 0, 0);
}

__device__ __forceinline__ f32x4 mfma32(f16x8 a, f16x8 b, f32x4 c) {
    return __builtin_amdgcn_mfma_f32_16x16x32_f16(a, b, c, 0, 0, 0);
}

// ---------------------------------------------------------------------------
// merged prep: x->fp16 | weights->fp16^T (log2e folded into wq) | vTp borders
//              | posT MFMA-A layout | zero page
// ---------------------------------------------------------------------------
__global__ __launch_bounds__(256) void prep(
    const float* __restrict__ x, const float* __restrict__ wq,
    const float* __restrict__ wkv, const float* __restrict__ wout,
    const float* __restrict__ posw, const float* __restrict__ posh,
    __half* __restrict__ x16, __half* __restrict__ wT, __half* __restrict__ woT,
    __half* __restrict__ posT, __half* __restrict__ vTp, __half* __restrict__ zp)
{
    const int bid = blockIdx.x, t = threadIdx.x;
    if (bid < 8192) {                       // x fp32 -> fp16
        const size_t i = ((size_t)bid * 256 + t) * 8;
        float4 a = *(const float4*)&x[i];
        float4 b = *(const float4*)&x[i + 4];
        __half2 h[4];
        h[0] = __floats2half2_rn(a.x, a.y);
        h[1] = __floats2half2_rn(a.z, a.w);
        h[2] = __floats2half2_rn(b.x, b.y);
        h[3] = __floats2half2_rn(b.z, b.w);
        *(float4*)&x16[i] = *(float4*)h;
    } else if (bid < 12288) {               // weights transposed
        const int id = (bid - 8192) * 256 + t;
        const int nr = id >> 9, k = id & 511;
        if (nr < 512) {
            wT[(size_t)nr * 512 + k] = __float2half(wq[k * 512 + nr] * (0.125f * LOG2E));
        } else if (nr < 1536) {
            wT[(size_t)nr * 512 + k] = __float2half(wkv[k * 1024 + (nr - 512)]);
        } else {
            woT[(size_t)(nr - 1536) * 512 + k] = __float2half(wout[k * 512 + (nr - 1536)]);
        }
    } else if (bid < 14336) {               // vTp x-borders -> 0
        const int id = (bid - 12288) * 256 + t;
        const int row = id >> 7, rem = id & 127;
        const int y = rem >> 1, side = rem & 1;
        f16x4 z = {(_Float16)0.f, (_Float16)0.f, (_Float16)0.f, (_Float16)0.f};
        *(f16x4*)(vTp + (size_t)row * VROW + y * 72 + side * 68) = z;
    } else if (bid < 14352) {               // posT [tb][idx(32)][d(64)]
        const int id = (bid - 14336) * 256 + t;
        const int tb = id >> 11, idx = (id >> 6) & 31, d = id & 63;
        const float* src = tb ? posh : posw;
        posT[id] = __float2half((idx < 31) ? src[d * 31 + idx] : 0.f);
    } else {                                // zero page (256 B)
        if (t < 16) {
            float4 z = make_float4(0.f, 0.f, 0.f, 0.f);
            *(float4*)(zp + t * 8) = z;
        }
    }
}

// ---------------------------------------------------------------------------
// fp16 MFMA GEMM, BM=BN=128, BK=64, 4 waves, DOUBLE-BUFFERED 2-phase:
// prefetch tile k+1 via global_load_lds while computing tile k; one
// asm-vmcnt(0) + raw s_barrier per K-step (prefetch lands under compute).
// LDS 64 KB -> 2 blocks/CU. Chunk-XOR swizzle (conflict-free ds_read_b128).
// 1-D grid, XCD-partitioned with bm-half split: live A set = 2 MB < L2.
// MODE 0: proj epilogue -> q16, k16, vTp (value part, padded transpose), NBN=12.
// MODE 1: fp32 store to outf, NBN=4.
// ---------------------------------------------------------------------------
template <int MODE, int NBN>
__global__ __launch_bounds__(256) void mfma_gemm(
    const __half* __restrict__ A, const __half* __restrict__ Bt,
    __half* __restrict__ q16, __half* __restrict__ k16, __half* __restrict__ vTp,
    float* __restrict__ outf)
{
    __shared__ __align__(16) char As[2 * 16384];   // 32 KB (2 buf x [128][64h] swz)
    __shared__ __align__(16) char Bs[2 * 16384];   // 32 KB

    const int t = threadIdx.x;
    const int l = t & 63, w = t >> 6;
    const int wr = w >> 1, wc = w & 1;
    const int lr = l & 15, hi = l >> 4;

    // XCD partition (RR dispatch: xcd = bid & 7) + bm-half split for L2
    const int bid = blockIdx.x;
    const int xcd = bid & 7, loc = bid >> 3;       // loc < 32*NBN
    const int half = loc / (16 * NBN);
    const int rem  = loc % (16 * NBN);
    const int bn   = rem >> 4;
    const int bm   = xcd * 32 + half * 16 + (rem & 15);

    f32x4 acc[4][4];
    #pragma unroll
    for (int i = 0; i < 4; ++i)
        #pragma unroll
        for (int j = 0; j < 4; ++j) acc[i][j] = (f32x4){0.f, 0.f, 0.f, 0.f};

    const int sch = (t & 7);
    const int srw = (t >> 3);

    auto STAGE = [&](int sel, int k0) {
        #pragma unroll
        for (int it = 0; it < 4; ++it) {
            const int row = it * 32 + srw;
            const int kk  = k0 + ((sch ^ (row & 7)) * 8);
            gload16(A + (size_t)(bm * 128 + row) * 512 + kk,
                    As + sel * 16384 + (it * 256 + w * 64) * 16);
        }
        #pragma unroll
        for (int it = 0; it < 4; ++it) {
            const int row = it * 32 + srw;
            const int kk  = k0 + ((sch ^ (row & 7)) * 8);
            gload16(Bt + (size_t)(bn * 128 + row) * 512 + kk,
                    Bs + sel * 16384 + (it * 256 + w * 64) * 16);
        }
    };

    STAGE(0, 0);
    asm volatile("s_waitcnt vmcnt(0)" ::: "memory");
    __builtin_amdgcn_s_barrier();

    #pragma unroll
    for (int k0 = 0; k0 < 512; k0 += 64) {
        const int sel = (k0 >> 6) & 1;
        if (k0 < 448) STAGE(sel ^ 1, k0 + 64);

        const char* Ab = As + sel * 16384;
        const char* Bb = Bs + sel * 16384;
        #pragma unroll
        for (int dc = 0; dc < 2; ++dc) {
            f16x8 af[4], bf[4];
            #pragma unroll
            for (int i = 0; i < 4; ++i) {
                const int ra = wr * 64 + i * 16 + lr;
                af[i] = *(const f16x8*)(Ab + ra * 128 + (((dc * 4 + hi) ^ (ra & 7)) * 16));
            }
            #pragma unroll
            for (int j = 0; j < 4; ++j) {
                const int rb = wc * 64 + j * 16 + lr;
                bf[j] = *(const f16x8*)(Bb + rb * 128 + (((dc * 4 + hi) ^ (rb & 7)) * 16));
            }
            #pragma unroll
            for (int i = 0; i < 4; ++i)
                #pragma unroll
                for (int j = 0; j < 4; ++j)
                    acc[i][j] = mfma32(af[i], bf[j], acc[i][j]);
        }

        if (k0 < 448) {
            asm volatile("s_waitcnt vmcnt(0)" ::: "memory");
            __builtin_amdgcn_s_barrier();
        }
    }

    const int lq = hi;
    #pragma unroll
    for (int i = 0; i < 4; ++i) {
        #pragma unroll
        for (int j = 0; j < 4; ++j) {
            const int row0 = bm * 128 + wr * 64 + i * 16 + lq * 4;
            const int col  = bn * 128 + wc * 64 + j * 16 + lr;
            if (MODE == 1) {
                #pragma unroll
                for (int r = 0; r < 4; ++r)
                    outf[(size_t)(row0 + r) * 512 + col] = acc[i][j][r];
            } else if (bn < 4) {
                #pragma unroll
                for (int r = 0; r < 4; ++r)
                    q16[(size_t)(row0 + r) * 512 + col] = __float2half(acc[i][j][r]);
            } else if (wc == 0) {           // key part
                const int head = bn - 4, d2 = j * 16 + lr;
                #pragma unroll
                for (int r = 0; r < 4; ++r)
                    k16[(size_t)(row0 + r) * 512 + head * 64 + d2] = __float2half(acc[i][j][r]);
            } else {                        // value part -> vTp[(b*8+head)*64+d][y*72+x+4]
                const int head = bn - 4, d2 = j * 16 + lr;
                const int bb = row0 >> 12, pix = row0 & 4095;  // 4 consecutive x, same y
                const int py = pix >> 6, px = pix & 63;
                f16x4 pv;
                #pragma unroll
                for (int r = 0; r < 4; ++r) pv[r] = (_Float16)acc[i][j][r];
                *(f16x4*)(vTp + ((size_t)((bb * 8 + head) * 64 + d2)) * VROW + py * 72 + px + 4) = pv;
            }
        }
    }
}

// ---------------------------------------------------------------------------
// MFMA halo attention, 4 waves, 3 barriers, LDS 40640 B -> 4 blocks/CU.
// Wave g owns key quarter [g*64,+64) for QK^T/softmax, dim quarter for PV.
// Pos bias: fp16 [23][66] tables; red2 overlays pos region after B1.
// Scores in log2 domain (log2e folded into wq) -> native exp2f.
// ---------------------------------------------------------------------------
__global__ __launch_bounds__(256, 4) void halo_attn(
    const __half* __restrict__ qbuf, const __half* __restrict__ kbuf,
    const __half* __restrict__ vTp, const __half* __restrict__ posT,
    const __half* __restrict__ zp, __half* __restrict__ obuf)
{
    __shared__ __align__(16) char KP[64 * 520];   // 33280 B: K(swz) -> P (pitch 520)
    __shared__ __align__(16) char POSB[6336];     // fp16 pos [2][24][66]; later red2
    __shared__ float red[4][64];                  // 1024 B

    __half* RW = (__half*)POSB;                   // [24][66] fp16, idx8 = idx-8
    __half* RH = (__half*)(POSB + 3168);
    float (*red2)[64] = (float(*)[64])POSB;       // overlay, live after B1

    // XCD swizzle: contiguous 512-block chunk (one batch) per XCD
    const int hw = blockIdx.x;
    const int wg = (hw & 7) * 512 + (hw >> 3);
    const int wb = wg & 7, hb = (wg >> 3) & 7, n = (wg >> 6) & 7, b = wg >> 9;
    const int t = threadIdx.x;
    const int l = t & 63, g = t >> 6;
    const int hi = l >> 4, c15 = l & 15;

    // ---- 1) issue K staging FIRST (global_load_lds, source pre-swizzled) ----
    #pragma unroll
    for (int it = 0; it < 8; ++it) {
        const int cid = it * 256 + t;
        const int S = cid * 16;                       // linear LDS byte
        const int row = S >> 7;                       // key 0..255
        const int d0h = (((S & 127) >> 4) ^ (row & 7)) * 8;   // halves
        const int ky = hb * 8 - 4 + (row >> 4);
        const int kx = wb * 8 - 4 + (row & 15);
        const bool ok = ((unsigned)ky < 64u) && ((unsigned)kx < 64u);
        const __half* src = ok ? (kbuf + ((size_t)((b * 64 + ky) * 64 + kx)) * 512 + n * 64 + d0h)
                               : zp;
        gload16(src, KP + (it * 256 + g * 64) * 16);
    }

    // ---- 2) V B-frags (16x16x32): lane (c15,hi) -> dim g*16+c15,
    //         keys kc*32 + hi*8 + j -> contiguous 16B in padded vT ----
    f16x8 vfrag[8];
    {
        const __half* vrow = vTp + ((size_t)((b * 8 + n) * 64 + g * 16 + c15)) * VROW;
        const int xoff = wb * 8 + (hi & 1) * 8;       // (wb*8-4 + kj0) + 4
        #pragma unroll
        for (int kc = 0; kc < 8; ++kc) {
            const int ki = kc * 2 + (hi >> 1);
            const int y = hb * 8 - 4 + ki;
            const __half* p = ((unsigned)y < 64u) ? (vrow + y * 72 + xoff) : zp;
            vfrag[kc] = *(const f16x8*)p;
        }
    }

    // ---- 3) Q fragments (B-operand of 16x16x32): qreg[qf][dc] ----
    f16x8 qreg[4][2];
    #pragma unroll
    for (int qf = 0; qf < 4; ++qf) {
        const int q = qf * 16 + c15;
        const size_t pix = (size_t)((b * 64 + hb * 8 + (q >> 3)) * 64 + wb * 8 + (q & 7));
        #pragma unroll
        for (int dc = 0; dc < 2; ++dc)
            qreg[qf][dc] = *(const f16x8*)(qbuf + pix * 512 + n * 64 + dc * 32 + hi * 8);
    }

    // ---- 4) pos MFMA straight from global posT (runs under K latency):
    //         wave g -> table tb=g>>1, idx-half ih=g&1 (8 MFMA) ----
    {
        const int tb = g >> 1, ih = g & 1;
        f32x4 accp[4];
        #pragma unroll
        for (int qf = 0; qf < 4; ++qf) accp[qf] = (f32x4){0.f, 0.f, 0.f, 0.f};
        #pragma unroll
        for (int dc = 0; dc < 2; ++dc) {
            const f16x8 a = *(const f16x8*)(posT + tb * 2048 + (ih * 16 + c15) * 64 + dc * 32 + hi * 8);
            #pragma unroll
            for (int qf = 0; qf < 4; ++qf)
                accp[qf] = mfma32(a, qreg[qf][dc], accp[qf]);
        }
        __half* dst = tb ? RH : RW;
        #pragma unroll
        for (int qf = 0; qf < 4; ++qf)
            #pragma unroll
            for (int r = 0; r < 4; ++r) {
                const unsigned idx8 = (unsigned)(ih * 16 + hi * 4 + r) - 8u;
                if (idx8 < 23u)
                    dst[idx8 * 66 + qf * 16 + c15] = __float2half(accp[qf][r]);
            }
    }
    __syncthreads();   // B0: K in LDS + pos tables visible (one combined barrier)

    // ---- QK^T: S^T frags, A=K (swizzled LDS, quarter g), B=Q regs ----
    f32x4 accs[4][4];
    #pragma unroll
    for (int kf = 0; kf < 4; ++kf)
        #pragma unroll
        for (int qf = 0; qf < 4; ++qf) accs[kf][qf] = (f32x4){0.f, 0.f, 0.f, 0.f};

    __builtin_amdgcn_s_setprio(1);
    #pragma unroll
    for (int kf = 0; kf < 4; ++kf) {
        const int row = g * 64 + kf * 16 + c15;
        #pragma unroll
        for (int dc = 0; dc < 2; ++dc) {
            const int off = (row * 128 + dc * 64 + hi * 16) ^ ((row & 7) << 4);
            f16x8 a = *(const f16x8*)(KP + off);
            #pragma unroll
            for (int qf = 0; qf < 4; ++qf)
                accs[kf][qf] = mfma32(a, qreg[qf][dc], accs[kf][qf]);
        }
    }
    __builtin_amdgcn_s_setprio(0);

    // ---- bias (fp16 tables) + per-quarter max ----
    float mq[4];
    #pragma unroll
    for (int qf = 0; qf < 4; ++qf) {
        const int q = qf * 16 + c15;
        const int qj = q & 7, qi = q >> 3;
        float pa[4], pb[4];
        #pragma unroll
        for (int r = 0; r < 4; ++r)  pa[r] = __half2float(RW[(hi * 4 + r + 7 - qj) * 66 + q]);
        #pragma unroll
        for (int kf = 0; kf < 4; ++kf) pb[kf] = __half2float(RH[(g * 4 + kf + 7 - qi) * 66 + q]);
        float mm = -1e30f;
        #pragma unroll
        for (int kf = 0; kf < 4; ++kf)
            #pragma unroll
            for (int r = 0; r < 4; ++r) {
                const float s = accs[kf][qf][r] + pa[r] + pb[kf];
                accs[kf][qf][r] = s;
                mm = fmaxf(mm, s);
            }
        mm = fmaxf(mm, __shfl_xor(mm, 16));
        mm = fmaxf(mm, __shfl_xor(mm, 32));
        mq[qf] = mm;
    }
    if (l < 16) {
        #pragma unroll
        for (int qf = 0; qf < 4; ++qf) red[g][qf * 16 + l] = mq[qf];
    }
    __syncthreads();   // B1: maxes visible; pos reads done -> POSB becomes red2

    // ---- exp2 + sums + pack P into LDS, pitch 520, 8B stores ----
    float sums[4];
    #pragma unroll
    for (int qf = 0; qf < 4; ++qf) {
        const int q = qf * 16 + c15;
        const float mfull = fmaxf(fmaxf(red[0][q], red[1][q]), fmaxf(red[2][q], red[3][q]));
        float ss = 0.f;
        #pragma unroll
        for (int kf = 0; kf < 4; ++kf)
            #pragma unroll
            for (int r = 0; r < 4; ++r) {
                const float p = exp2f(accs[kf][qf][r] - mfull);   // scores in log2 domain
                accs[kf][qf][r] = p;
                ss += p;
            }
        ss += __shfl_xor(ss, 16);
        ss += __shfl_xor(ss, 32);
        sums[qf] = ss;
        #pragma unroll
        for (int kf = 0; kf < 4; ++kf) {
            __half2 h01 = __floats2half2_rn(accs[kf][qf][0], accs[kf][qf][1]);
            __half2 h23 = __floats2half2_rn(accs[kf][qf][2], accs[kf][qf][3]);
            uint2 wv;
            wv.x = *(unsigned*)&h01;
            wv.y = *(unsigned*)&h23;
            *(uint2*)(KP + q * 520 + (g * 64 + kf * 16 + hi * 4) * 2) = wv;
        }
    }
    if (l < 16) {
        #pragma unroll
        for (int qf = 0; qf < 4; ++qf) red2[g][qf * 16 + l] = sums[qf];
    }
    __syncthreads();   // B2: P + sums visible

    // ---- PV via 16x16x32: wave g owns dims [g*16,+16), 8 kc steps. ----
    f32x4 acco[4];
    #pragma unroll
    for (int qf = 0; qf < 4; ++qf) acco[qf] = (f32x4){0.f, 0.f, 0.f, 0.f};
    __builtin_amdgcn_s_setprio(1);
    #pragma unroll
    for (int kc = 0; kc < 8; ++kc) {
        const f16x8 bf = vfrag[kc];
        #pragma unroll
        for (int qf = 0; qf < 4; ++qf) {
            const char* pp = KP + (qf * 16 + c15) * 520 + kc * 64 + hi * 16;
            const f16x4 p0 = *(const f16x4*)pp;
            const f16x4 p1 = *(const f16x4*)(pp + 8);
            const f16x8 af = __builtin_shufflevector(p0, p1, 0, 1, 2, 3, 4, 5, 6, 7);
            acco[qf] = mfma32(af, bf, acco[qf]);
        }
    }
    __builtin_amdgcn_s_setprio(0);

    // ---- normalize (fast rcp) + store ----
    #pragma unroll
    for (int qf = 0; qf < 4; ++qf) {
        #pragma unroll
        for (int r = 0; r < 4; ++r) {
            const int q = qf * 16 + hi * 4 + r;
            const float den = red2[0][q] + red2[1][q] + red2[2][q] + red2[3][q];
            const float v = acco[qf][r] * __builtin_amdgcn_rcpf(den);
            const size_t pix = (size_t)((b * 64 + hb * 8 + (q >> 3)) * 64 + wb * 8 + (q & 7));
            obuf[pix * 512 + n * 64 + g * 16 + c15] = __float2half(v);
        }
    }
}

// ---------------------------------------------------------------------------
extern "C" void kernel_launch(void* const* d_in, const int* in_sizes, int n_in,
                              void* d_out, int out_size, void* d_ws, size_t ws_size,
                              hipStream_t stream)
{
    const float* x    = (const float*)d_in[0];
    const float* wq   = (const float*)d_in[1];
    const float* wkv  = (const float*)d_in[2];
    const float* wout = (const float*)d_in[3];
    const float* posw = (const float*)d_in[4];
    const float* posh = (const float*)d_in[5];
    float* out = (float*)d_out;

    // fp16 workspace (~174 MB)
    const size_t NPIX = (size_t)M_TOT * 512;
    const size_t NVTP = (size_t)64 * 64 * VROW;    // 18.87M halves
    __half* x16  = (__half*)d_ws;            // 33.5 MB
    __half* wT   = x16 + NPIX;               // 1.5 MB
    __half* woT  = wT + (size_t)1536 * 512;  // 0.5 MB
    __half* q16  = woT + (size_t)512 * 512;  // 33.5 MB
    __half* k16  = q16 + NPIX;               // 33.5 MB
    __half* vTp  = k16 + NPIX;               // 37.7 MB
    __half* o16  = vTp + NVTP;               // 33.5 MB
    __half* zp   = o16 + NPIX;               // 256 B zero page
    __half* posT = zp + 128;                 // 8 KB pos tables (MFMA-A layout)

    prep<<<14353, 256, 0, stream>>>(x, wq, wkv, wout, posw, posh,
                                    x16, wT, woT, posT, vTp, zp);

    mfma_gemm<0, 12><<<3072, 256, 0, stream>>>(x16, wT, q16, k16, vTp, nullptr);

    halo_attn<<<4096, 256, 0, stream>>>(q16, k16, vTp, posT, zp, o16);

    mfma_gemm<1, 4><<<1024, 256, 0, stream>>>(o16, woT, nullptr, nullptr, nullptr, out);
}